// Round 9
// baseline (274.288 us; speedup 1.0000x reference)
//
#include <hip/hip_runtime.h>
#include <hip/hip_bf16.h>

// RPEMultiHeadAttention, MI355X (gfx950).
// Math: rel-pos terms (attn2/attn3) are constant along the softmax axis ->
// softmax shift-invariance -> dead. Reference == plain MHA, scale 1/sqrt(192).
// All external I/O is float32; intermediates bf16 (MFMA), f32 accumulate.
//
// v19 = barrier-free flash: K/V read DIRECT from global (L1/L2), no LDS
// staging, no main-loop barriers, no kh split.
//  - Rationale: learn_hip m169 (stage only when data doesn't cache-fit);
//    K/V per (b,h) = 256KB, 8 bh/XCD = 2MB <= 4MB L2. Prior session's
//    barrier-free failure modes (reg-caching K -> VGPR blowup; per-wave
//    refetch 1.07GB L2) are both gone under sigma-PV: fragments go
//    global->MFMA directly, and all 4 waves read IDENTICAL K/V addresses
//    (L1 dedup). L2 floor ~31us < staged ~38us.
//  - Block 256 = 4 independent waves; each owns 16 q-rows, sweeps 16 kv-tiles
//    of 64. kf: 2x16B/lane (dense 128B rows); vf: 4x8B/lane (full row/iter).
//  - Epilogue: WoS stage + wave-local Pe + ONE barrier + out-proj + atomics.
//    LDS 18432 B total.
//  - __launch_bounds__(256,4): cap 128. v15/v18 lesson: 85-caps collapse the
//    allocator to 40+scratch (2x confirmed) -- never cap below natural need.
// Retained: sigma-permuted PV, ones-MFMA L, swapped QK^T, raw exp2, setprio.
// Tripwire: flash >= 40us or e2e > 132 => revert to v16 staged structure.
// Harness note: ~2x 256MiB poison fills (~86 us) dominate e2e.

#define N_HEAD 8
#define SEQ    1024
#define SC2    0.10411804386480816f  // (1/sqrt(192)) * log2(e)

typedef __hip_bfloat16 bf16;
typedef __bf16 bf16x8 __attribute__((ext_vector_type(8)));
typedef __bf16 bf16x4 __attribute__((ext_vector_type(4)));
typedef float  f32x4  __attribute__((ext_vector_type(4)));

// ---------------------------------------------------------------------------
// Kernel 1: q1/k1/v1 = X @ W + b via MFMA (unchanged from v16/v18).
// ---------------------------------------------------------------------------
__global__ __launch_bounds__(256)
void qkv_mfma_kernel(const float* __restrict__ Xq, const float* __restrict__ Xk,
                     const float* __restrict__ Xv,
                     const float* __restrict__ Wq, const float* __restrict__ Wk,
                     const float* __restrict__ Wv,
                     const float* __restrict__ bq, const float* __restrict__ bk,
                     const float* __restrict__ bv,
                     const float* __restrict__ bo, float* __restrict__ out,
                     bf16* __restrict__ Qh, bf16* __restrict__ Kh,
                     bf16* __restrict__ Vt)
{
    const int rt    = blockIdx.x;   // rows rt*128 .. +127 of [8192]
    const int ct    = blockIdx.y;   // head (cols ct*64 .. +63)
    const int which = blockIdx.z;   // 0=q 1=k 2=v

    const float* __restrict__ X    = which == 0 ? Xq : (which == 1 ? Xk : Xv);
    const float* __restrict__ W    = which == 0 ? Wq : (which == 1 ? Wk : Wv);
    const float* __restrict__ bias = which == 0 ? bq : (which == 1 ? bk : bv);

    __shared__ __align__(16) bf16 Xs [128 * 72];  // A tiles [m][k]; reused as C overlay
    __shared__ __align__(16) bf16 Wts[64 * 72];   // B tiles [n][k]
    __shared__ float Bs[64];

    const int tid  = threadIdx.x;
    const int w4   = tid >> 6;
    const int lane = tid & 63;
    const int t16  = lane & 15;
    const int quad = lane >> 4;

    if (tid < 64) Bs[tid] = bias[ct * 64 + tid];
    // stage X (f32 -> bf16): 128x64, coalesced float4 reads
    for (int i = tid; i < 2048; i += 256) {
        const int r = i >> 4, c4 = (i & 15) << 2;
        const float4 v = *(const float4*)&X[(size_t)(rt * 128 + r) * 64 + c4];
        bf16 t[4] = {__float2bfloat16(v.x), __float2bfloat16(v.y),
                     __float2bfloat16(v.z), __float2bfloat16(v.w)};
        *(bf16x4*)&Xs[r * 72 + c4] = *(bf16x4*)t;
    }
    // stage W^T slice: Wts[n][k] = W[k][ct*64+n], coalesced float4 row reads
    for (int i = tid; i < 1024; i += 256) {
        const int k = i >> 4, n4 = (i & 15) << 2;
        const float4 w = *(const float4*)&W[(size_t)k * 512 + ct * 64 + n4];
        Wts[(n4 + 0) * 72 + k] = __float2bfloat16(w.x);
        Wts[(n4 + 1) * 72 + k] = __float2bfloat16(w.y);
        Wts[(n4 + 2) * 72 + k] = __float2bfloat16(w.z);
        Wts[(n4 + 3) * 72 + k] = __float2bfloat16(w.w);
    }
    // bias-init out for flash's atomic accumulation (runs before flash in-stream)
    if (which == 0 && ct == 0) {
        for (int i = tid; i < 2048; i += 256) {
            const int r = i >> 4, c4 = (i & 15) << 2;
            *(float4*)&out[(size_t)(rt * 128 + r) * 64 + c4] = *(const float4*)&bo[c4];
        }
    }
    __syncthreads();

    // B fragments (shared across both row-sets)
    bf16x8 bf0[4], bf1[4];
#pragma unroll
    for (int nt = 0; nt < 4; nt++) {
        bf0[nt] = *(const bf16x8*)&Wts[(nt * 16 + t16) * 72 + 0  + quad * 8];
        bf1[nt] = *(const bf16x8*)&Wts[(nt * 16 + t16) * 72 + 32 + quad * 8];
    }

    f32x4 acc[2][4];
#pragma unroll
    for (int rs = 0; rs < 2; rs++) {
        const int m = rs * 64 + w4 * 16 + t16;
        const bf16x8 af0 = *(const bf16x8*)&Xs[m * 72 + 0  + quad * 8];
        const bf16x8 af1 = *(const bf16x8*)&Xs[m * 72 + 32 + quad * 8];
#pragma unroll
        for (int nt = 0; nt < 4; nt++) {
            acc[rs][nt] = (f32x4){0.f, 0.f, 0.f, 0.f};
            acc[rs][nt] = __builtin_amdgcn_mfma_f32_16x16x32_bf16(af0, bf0[nt], acc[rs][nt], 0, 0, 0);
            acc[rs][nt] = __builtin_amdgcn_mfma_f32_16x16x32_bf16(af1, bf1[nt], acc[rs][nt], 0, 0, 0);
        }
    }

    const int b     = rt >> 3;
    const int sbase = (rt & 7) * 128;

    __syncthreads();   // all waves done reading Xs/Wts -> overlay is safe

    if (which < 2) {
        // Q/K: stage C into LDS overlay [128 r][72], then contiguous stores
        bf16* Cs = Xs;
        const float sc = (which == 0) ? SC2 : 1.0f;   // fold softmax scale into Q
#pragma unroll
        for (int rs = 0; rs < 2; rs++)
#pragma unroll
            for (int nt = 0; nt < 4; nt++)
#pragma unroll
                for (int rr = 0; rr < 4; rr++) {
                    const int row = rs * 64 + w4 * 16 + quad * 4 + rr;
                    Cs[row * 72 + nt * 16 + t16] =
                        __float2bfloat16((acc[rs][nt][rr] + Bs[nt * 16 + t16]) * sc);
                }
        __syncthreads();
        bf16* O = which == 0 ? Qh : Kh;
        for (int i = tid; i < 1024; i += 256) {
            const int r = i >> 3, c8 = (i & 7) << 3;
            *(bf16x8*)&O[(((size_t)b * N_HEAD + ct) * SEQ + sbase + r) * 64 + c8] =
                *(const bf16x8*)&Cs[r * 72 + c8];
        }
    } else {
        // V: transpose via LDS overlay, then coalesced stores
        bf16* VtS = Xs;   // [64 c][136 r]
#pragma unroll
        for (int rs = 0; rs < 2; rs++)
#pragma unroll
            for (int nt = 0; nt < 4; nt++)
#pragma unroll
                for (int rr = 0; rr < 4; rr++) {
                    const int rloc = rs * 64 + w4 * 16 + quad * 4 + rr;
                    VtS[(nt * 16 + t16) * 136 + rloc] =
                        __float2bfloat16(acc[rs][nt][rr] + Bs[nt * 16 + t16]);
                }
        __syncthreads();
        for (int i = tid; i < 1024; i += 256) {
            const int c = i >> 4, r8 = (i & 15) << 3;
            *(bf16x8*)&Vt[(((size_t)b * N_HEAD + ct) * 64 + c) * SEQ + sbase + r8] =
                *(const bf16x8*)&VtS[c * 136 + r8];
        }
    }
}

// ---------------------------------------------------------------------------
// Kernel 2: flash attention + fused out-proj. BARRIER-FREE main loop.
// Grid (bh=64, qt=16): XCD = bh%8, all qt-blocks of one (b,h) share an XCD
// L2 (K/V 256KB/bh, 2MB/XCD resident). Block = 256 threads = 4 independent
// waves; wave w4 owns q-rows qt*64 + w4*16 .. +15, sweeps all 1024 kv in
// 16 tiles of 64. All 4 waves read IDENTICAL K/V addresses -> L1 dedup.
// Swapped QK^T: Sf[nt] = S[kv=nt*16+quad*4+rr][q=t16].
// Sigma-PV: A-frag = lane's own exp2 regs; V B-frag = 4x 8B global loads
// (full 128B V-row coverage per iter). l via ones-MFMA (keying == Of).
// Epilogue: WoS cooperative stage + wave-local Pe + ONE barrier + out-proj
// (all 4 nt per wave) + atomics. LDS 18432 B.
// ---------------------------------------------------------------------------
__global__ __launch_bounds__(256, 4)
void flash_attn_kernel(const bf16* __restrict__ Qh, const bf16* __restrict__ Kh,
                       const bf16* __restrict__ Vt, const float* __restrict__ Wo,
                       float* __restrict__ out)
{
    const int bhx  = blockIdx.x;    // 0..63
    const int qt   = blockIdx.y;    // 0..15 (64 q-rows each)
    const int b    = bhx >> 3;
    const int h    = bhx & 7;
    const int tid  = threadIdx.x;
    const int w4   = tid >> 6;      // 0..3 (q-group of 16 rows)
    const int lane = tid & 63;
    const int t16  = lane & 15;
    const int quad = lane >> 4;

    const size_t bh = (size_t)b * N_HEAD + h;
    const bf16* __restrict__ Qp  = Qh + bh * (SEQ * 64);  // [1024][64], pre-scaled
    const bf16* __restrict__ Kp  = Kh + bh * (SEQ * 64);  // [1024][64]
    const bf16* __restrict__ Vtp = Vt + bh * (64 * SEQ);  // [64][1024]

    __shared__ __align__(16) bf16 smem[9216];             // 18432 B
    bf16* WoS = smem;                 // [64][72] : elems [0, 4608)
    bf16* Pe  = smem + 4608;          // [4 w4][16*72] : elems [4608, 9216)

    // Q fragments for this wave's 16 rows
    const int qrow = qt * 64 + w4 * 16 + t16;
    const bf16x8 qf0 = *(const bf16x8*)(Qp + (size_t)qrow * 64 + 0  + quad * 8);
    const bf16x8 qf1 = *(const bf16x8*)(Qp + (size_t)qrow * 64 + 32 + quad * 8);

    // constant all-ones B fragment for the l row-sum MFMA
    bf16x8 vones;
#pragma unroll
    for (int j = 0; j < 8; j++) vones[j] = (__bf16)1.0f;

    f32x4 Of[4];
    f32x4 Lf = (f32x4){0.f, 0.f, 0.f, 0.f};
#pragma unroll
    for (int nt = 0; nt < 4; nt++) Of[nt] = (f32x4){0.f, 0.f, 0.f, 0.f};

    // ---- main loop: 16 kv-tiles of 64, no LDS, no barriers ----
    for (int kv0 = 0; kv0 < SEQ; kv0 += 64) {
        // Phase A: S^T = K Q^T (swapped). kf read direct from global:
        // row kv0+nt*16+t16 (128B), cols [quad*8..+8) and [32+quad*8..+8).
        f32x4 Sf[4];
        __builtin_amdgcn_s_setprio(1);
#pragma unroll
        for (int nt = 0; nt < 4; nt++) {
            const bf16* krow = Kp + (size_t)(kv0 + nt * 16 + t16) * 64;
            const bf16x8 kf0 = *(const bf16x8*)(krow + 0  + quad * 8);
            const bf16x8 kf1 = *(const bf16x8*)(krow + 32 + quad * 8);
            Sf[nt] = (f32x4){0.f, 0.f, 0.f, 0.f};
            Sf[nt] = __builtin_amdgcn_mfma_f32_16x16x32_bf16(kf0, qf0, Sf[nt], 0, 0, 0);
            Sf[nt] = __builtin_amdgcn_mfma_f32_16x16x32_bf16(kf1, qf1, Sf[nt], 0, 0, 0);
        }
        __builtin_amdgcn_s_setprio(0);

        // Phase B: p = exp2(S), packed in-register sigma-ordered.
        // slot (quad,j) <-> kv_local = (j>=4)*16 + quad*4 + (j&3) (+32 for hi)
        bf16 tl[8], th[8];
#pragma unroll
        for (int nt = 0; nt < 4; nt++)
#pragma unroll
            for (int rr = 0; rr < 4; rr++) {
                const float p = __builtin_amdgcn_exp2f(Sf[nt][rr]);
                if (nt < 2) tl[nt * 4 + rr]       = __float2bfloat16(p);
                else        th[(nt - 2) * 4 + rr] = __float2bfloat16(p);
            }
        const bf16x8 pfl = *(bf16x8*)tl;
        const bf16x8 pfh = *(bf16x8*)th;

        // Phase C: O += P V (+ l via ones MFMA). vf read direct from global,
        // sigma-ordered: V-row d=nt*16+t16, cols kv0+{0,16,32,48}+quad*4.
        __builtin_amdgcn_s_setprio(1);
#pragma unroll
        for (int nt = 0; nt < 4; nt++) {
            const bf16* vrow = Vtp + (size_t)(nt * 16 + t16) * SEQ + kv0;
            bf16 vl[8], vh[8];
            *(bf16x4*)&vl[0] = *(const bf16x4*)(vrow + 0  + quad * 4);
            *(bf16x4*)&vl[4] = *(const bf16x4*)(vrow + 16 + quad * 4);
            *(bf16x4*)&vh[0] = *(const bf16x4*)(vrow + 32 + quad * 4);
            *(bf16x4*)&vh[4] = *(const bf16x4*)(vrow + 48 + quad * 4);
            Of[nt] = __builtin_amdgcn_mfma_f32_16x16x32_bf16(pfl, *(const bf16x8*)vl, Of[nt], 0, 0, 0);
            Of[nt] = __builtin_amdgcn_mfma_f32_16x16x32_bf16(pfh, *(const bf16x8*)vh, Of[nt], 0, 0, 0);
        }
        Lf = __builtin_amdgcn_mfma_f32_16x16x32_bf16(pfl, vones, Lf, 0, 0, 0);
        Lf = __builtin_amdgcn_mfma_f32_16x16x32_bf16(pfh, vones, Lf, 0, 0, 0);
        __builtin_amdgcn_s_setprio(0);
    }

    // ---- epilogue: ONE barrier ----
    // stage Wo^T slice from f32: WoS[c][kk] = Wo[h*64+kk][c], coalesced rows
    for (int i = tid; i < 4096; i += 256) {
        const int kk = i >> 6, c = i & 63;
        WoS[c * 72 + kk] = __float2bfloat16(Wo[(size_t)(h * 64 + kk) * 64 + c]);
    }
    // normalize into Pe[w4] (wave-local; Lf[rr] keyed q=quad*4+rr == Of keying)
    {
        float inv_l[4];
#pragma unroll
        for (int rr = 0; rr < 4; rr++) inv_l[rr] = 1.0f / Lf[rr];
        bf16* Pew = Pe + w4 * 1152;
#pragma unroll
        for (int nt = 0; nt < 4; nt++)
#pragma unroll
            for (int rr = 0; rr < 4; rr++)
                Pew[(quad * 4 + rr) * 72 + nt * 16 + t16] =
                    __float2bfloat16(Of[nt][rr] * inv_l[rr]);
    }
    __syncthreads();   // WoS staged (cooperative) + Pe written

    {   // out-proj: each wave projects its own 16 rows x all 64 cols
        const bf16* Pew = Pe + w4 * 1152;
        const bf16x8 pf0 = *(const bf16x8*)&Pew[t16 * 72 + 0  + quad * 8];
        const bf16x8 pf1 = *(const bf16x8*)&Pew[t16 * 72 + 32 + quad * 8];

        const int srow_base = qt * 64 + w4 * 16 + quad * 4;
#pragma unroll
        for (int nt = 0; nt < 4; nt++) {
            const bf16x8 wf0 = *(const bf16x8*)&WoS[(nt * 16 + t16) * 72 + 0  + quad * 8];
            const bf16x8 wf1 = *(const bf16x8*)&WoS[(nt * 16 + t16) * 72 + 32 + quad * 8];
            f32x4 R = (f32x4){0.f, 0.f, 0.f, 0.f};
            R = __builtin_amdgcn_mfma_f32_16x16x32_bf16(pf0, wf0, R, 0, 0, 0);
            R = __builtin_amdgcn_mfma_f32_16x16x32_bf16(pf1, wf1, R, 0, 0, 0);
#pragma unroll
            for (int rr = 0; rr < 4; rr++)
                atomicAdd(&out[((size_t)b * SEQ + srow_base + rr) * 64 + nt * 16 + t16],
                          R[rr]);
        }
    }
}

// ---------------------------------------------------------------------------
extern "C" void kernel_launch(void* const* d_in, const int* in_sizes, int n_in,
                              void* d_out, int out_size, void* d_ws, size_t ws_size,
                              hipStream_t stream)
{
    const float* query = (const float*)d_in[0];
    const float* key_  = (const float*)d_in[1];
    const float* value = (const float*)d_in[2];
    const float* Wq    = (const float*)d_in[3];
    const float* bq    = (const float*)d_in[4];
    const float* Wk    = (const float*)d_in[5];
    const float* bk    = (const float*)d_in[6];
    const float* Wv    = (const float*)d_in[7];
    const float* bv    = (const float*)d_in[8];
    const float* Wo    = (const float*)d_in[9];
    const float* bo    = (const float*)d_in[10];
    // d_in[11..15] dead (softmax shift-invariance)

    float* out = (float*)d_out;
    char* ws   = (char*)d_ws;
    bf16* Qh = (bf16*)(ws + (size_t) 0 * 1024 * 1024);   // [B,H,S,64]  8 MB
    bf16* Kh = (bf16*)(ws + (size_t) 8 * 1024 * 1024);   //             8 MB
    bf16* Vt = (bf16*)(ws + (size_t)16 * 1024 * 1024);   // [B,H,64,S]  8 MB

    qkv_mfma_kernel<<<dim3(64, 8, 3), 256, 0, stream>>>(
        query, key_, value, Wq, Wk, Wv, bq, bk, bv, bo, out, Qh, Kh, Vt);
    flash_attn_kernel<<<dim3(64, 16), 256, 0, stream>>>(Qh, Kh, Vt, Wo, out);
}

// Round 10
// 131.029 us; speedup vs baseline: 2.0933x; 2.0933x over previous
//
#include <hip/hip_runtime.h>
#include <hip/hip_bf16.h>

// RPEMultiHeadAttention, MI355X (gfx950).
// Math: rel-pos terms (attn2/attn3) are constant along the softmax axis ->
// softmax shift-invariance -> dead. Reference == plain MHA, scale 1/sqrt(192).
// All external I/O is float32; intermediates bf16 (MFMA), f32 accumulate.
//
// v20 = v16 (best verified: e2e 132.1us) + Wo-prestage hoist.
//  - WoS LDS region (bytes [43008,52224)) is disjoint from main-loop K/V
//    buffers ([0,36864)) -> stage Wo in the PROLOGUE, overlapping its loads
//    with the first K/V tiles; epilogue tail shortens by one staging pass.
// Falsified levers (do NOT retry): VALU diet (v14 null), 1-barrier dbuf
// (v17 -2us), VGPR caps < natural need (v15/v18: allocator collapses to 40
// + full scratch spill, 2x confirmed), barrier-free direct-global (v19: 4x
// regression -- LDS staging IS the latency-hiding mechanism here).
// Proven wins: swapped QK^T (mfma(K,Q)), sigma-permuted PV (P never leaves
// registers), (512,4) bounds, parallel 8-wave epilogue, ones-MFMA L.
// Harness note: ~2x 256MiB poison fills (~86 us) dominate e2e; addressable
// budget is flash (<42us) + qkv + gaps.

#define N_HEAD 8
#define SEQ    1024
#define SC2    0.10411804386480816f  // (1/sqrt(192)) * log2(e)

typedef __hip_bfloat16 bf16;
typedef __bf16 bf16x8 __attribute__((ext_vector_type(8)));
typedef __bf16 bf16x4 __attribute__((ext_vector_type(4)));
typedef float  f32x4  __attribute__((ext_vector_type(4)));

// ---------------------------------------------------------------------------
// Kernel 1: q1/k1/v1 = X @ W + b via MFMA (unchanged from v16).
// ---------------------------------------------------------------------------
__global__ __launch_bounds__(256)
void qkv_mfma_kernel(const float* __restrict__ Xq, const float* __restrict__ Xk,
                     const float* __restrict__ Xv,
                     const float* __restrict__ Wq, const float* __restrict__ Wk,
                     const float* __restrict__ Wv,
                     const float* __restrict__ bq, const float* __restrict__ bk,
                     const float* __restrict__ bv,
                     const float* __restrict__ bo, float* __restrict__ out,
                     bf16* __restrict__ Qh, bf16* __restrict__ Kh,
                     bf16* __restrict__ Vt)
{
    const int rt    = blockIdx.x;   // rows rt*128 .. +127 of [8192]
    const int ct    = blockIdx.y;   // head (cols ct*64 .. +63)
    const int which = blockIdx.z;   // 0=q 1=k 2=v

    const float* __restrict__ X    = which == 0 ? Xq : (which == 1 ? Xk : Xv);
    const float* __restrict__ W    = which == 0 ? Wq : (which == 1 ? Wk : Wv);
    const float* __restrict__ bias = which == 0 ? bq : (which == 1 ? bk : bv);

    __shared__ __align__(16) bf16 Xs [128 * 72];  // A tiles [m][k]; reused as C overlay
    __shared__ __align__(16) bf16 Wts[64 * 72];   // B tiles [n][k]
    __shared__ float Bs[64];

    const int tid  = threadIdx.x;
    const int w4   = tid >> 6;
    const int lane = tid & 63;
    const int t16  = lane & 15;
    const int quad = lane >> 4;

    if (tid < 64) Bs[tid] = bias[ct * 64 + tid];
    // stage X (f32 -> bf16): 128x64, coalesced float4 reads
    for (int i = tid; i < 2048; i += 256) {
        const int r = i >> 4, c4 = (i & 15) << 2;
        const float4 v = *(const float4*)&X[(size_t)(rt * 128 + r) * 64 + c4];
        bf16 t[4] = {__float2bfloat16(v.x), __float2bfloat16(v.y),
                     __float2bfloat16(v.z), __float2bfloat16(v.w)};
        *(bf16x4*)&Xs[r * 72 + c4] = *(bf16x4*)t;
    }
    // stage W^T slice: Wts[n][k] = W[k][ct*64+n], coalesced float4 row reads
    for (int i = tid; i < 1024; i += 256) {
        const int k = i >> 4, n4 = (i & 15) << 2;
        const float4 w = *(const float4*)&W[(size_t)k * 512 + ct * 64 + n4];
        Wts[(n4 + 0) * 72 + k] = __float2bfloat16(w.x);
        Wts[(n4 + 1) * 72 + k] = __float2bfloat16(w.y);
        Wts[(n4 + 2) * 72 + k] = __float2bfloat16(w.z);
        Wts[(n4 + 3) * 72 + k] = __float2bfloat16(w.w);
    }
    // bias-init out for flash's atomic accumulation (runs before flash in-stream)
    if (which == 0 && ct == 0) {
        for (int i = tid; i < 2048; i += 256) {
            const int r = i >> 4, c4 = (i & 15) << 2;
            *(float4*)&out[(size_t)(rt * 128 + r) * 64 + c4] = *(const float4*)&bo[c4];
        }
    }
    __syncthreads();

    // B fragments (shared across both row-sets)
    bf16x8 bf0[4], bf1[4];
#pragma unroll
    for (int nt = 0; nt < 4; nt++) {
        bf0[nt] = *(const bf16x8*)&Wts[(nt * 16 + t16) * 72 + 0  + quad * 8];
        bf1[nt] = *(const bf16x8*)&Wts[(nt * 16 + t16) * 72 + 32 + quad * 8];
    }

    f32x4 acc[2][4];
#pragma unroll
    for (int rs = 0; rs < 2; rs++) {
        const int m = rs * 64 + w4 * 16 + t16;
        const bf16x8 af0 = *(const bf16x8*)&Xs[m * 72 + 0  + quad * 8];
        const bf16x8 af1 = *(const bf16x8*)&Xs[m * 72 + 32 + quad * 8];
#pragma unroll
        for (int nt = 0; nt < 4; nt++) {
            acc[rs][nt] = (f32x4){0.f, 0.f, 0.f, 0.f};
            acc[rs][nt] = __builtin_amdgcn_mfma_f32_16x16x32_bf16(af0, bf0[nt], acc[rs][nt], 0, 0, 0);
            acc[rs][nt] = __builtin_amdgcn_mfma_f32_16x16x32_bf16(af1, bf1[nt], acc[rs][nt], 0, 0, 0);
        }
    }

    const int b     = rt >> 3;
    const int sbase = (rt & 7) * 128;

    __syncthreads();   // all waves done reading Xs/Wts -> overlay is safe

    if (which < 2) {
        // Q/K: stage C into LDS overlay [128 r][72], then contiguous stores
        bf16* Cs = Xs;
        const float sc = (which == 0) ? SC2 : 1.0f;   // fold softmax scale into Q
#pragma unroll
        for (int rs = 0; rs < 2; rs++)
#pragma unroll
            for (int nt = 0; nt < 4; nt++)
#pragma unroll
                for (int rr = 0; rr < 4; rr++) {
                    const int row = rs * 64 + w4 * 16 + quad * 4 + rr;
                    Cs[row * 72 + nt * 16 + t16] =
                        __float2bfloat16((acc[rs][nt][rr] + Bs[nt * 16 + t16]) * sc);
                }
        __syncthreads();
        bf16* O = which == 0 ? Qh : Kh;
        for (int i = tid; i < 1024; i += 256) {
            const int r = i >> 3, c8 = (i & 7) << 3;
            *(bf16x8*)&O[(((size_t)b * N_HEAD + ct) * SEQ + sbase + r) * 64 + c8] =
                *(const bf16x8*)&Cs[r * 72 + c8];
        }
    } else {
        // V: transpose via LDS overlay, then coalesced stores
        bf16* VtS = Xs;   // [64 c][136 r]
#pragma unroll
        for (int rs = 0; rs < 2; rs++)
#pragma unroll
            for (int nt = 0; nt < 4; nt++)
#pragma unroll
                for (int rr = 0; rr < 4; rr++) {
                    const int rloc = rs * 64 + w4 * 16 + quad * 4 + rr;
                    VtS[(nt * 16 + t16) * 136 + rloc] =
                        __float2bfloat16(acc[rs][nt][rr] + Bs[nt * 16 + t16]);
                }
        __syncthreads();
        for (int i = tid; i < 1024; i += 256) {
            const int c = i >> 4, r8 = (i & 15) << 3;
            *(bf16x8*)&Vt[(((size_t)b * N_HEAD + ct) * 64 + c) * SEQ + sbase + r8] =
                *(const bf16x8*)&VtS[c * 136 + r8];
        }
    }
}

// ---------------------------------------------------------------------------
// Kernel 2: flash attention + fused out-proj (v16 structure).
// Grid (bh=64, qt=8): XCD = bh%8, all qt-blocks of one (b,h) share an XCD L2.
// Block = 512 threads = {4 waves x 2 k-halves} x 2 row-sets of 16.
// Swapped QK^T (mfma(K,Q)): Sf col=q=t16, row=kv.
// PV with sigma-permuted k-slots: A-frag = lane's own exp2(Sf) registers
// (no P LDS round-trip); V B-frag = 4x ds_read_b64 at {0,16,32,48}+quad*4.
// l via ones-column MFMA (keying matches Of -> no cross-lane normalize).
// Wo staged in the PROLOGUE (LDS bytes [43008,52224) disjoint from K/V).
// Epilogue: all 8 waves parallel; Pe overlays dead Xch after 2nd barrier.
// LDS 52224 B; occupancy VGPR-limited at 2 blocks/CU (128-VGPR cap).
// ---------------------------------------------------------------------------
__global__ __launch_bounds__(512, 4)
void flash_attn_kernel(const bf16* __restrict__ Qh, const bf16* __restrict__ Kh,
                       const bf16* __restrict__ Vt, const float* __restrict__ Wo,
                       float* __restrict__ out)
{
    const int bhx  = blockIdx.x;    // 0..63
    const int qt   = blockIdx.y;    // 0..7 (128 q-rows each)
    const int b    = bhx >> 3;
    const int h    = bhx & 7;
    const int tid  = threadIdx.x;
    const int wave = tid >> 6;      // 0..7
    const int w4   = wave & 3;
    const int kh   = wave >> 2;     // k-half: 0 -> kv 0..63, 1 -> kv 64..127 of tile
    const int lane = tid & 63;
    const int t16  = lane & 15;
    const int quad = lane >> 4;

    const size_t bh = (size_t)b * N_HEAD + h;
    const bf16* __restrict__ Qp  = Qh + bh * (SEQ * 64);  // [1024][64], pre-scaled
    const bf16* __restrict__ Kp  = Kh + bh * (SEQ * 64);  // [1024][64]
    const bf16* __restrict__ Vtp = Vt + bh * (64 * SEQ);  // [64][1024]

    __shared__ __align__(16) bf16 smem[26112];            // 52224 B
    bf16* KsB  = smem;                // [2][64*72]   18432 B
    bf16* VtsB = smem + 9216;         // [2][64*72]   18432 B  (ends byte 36864)
    bf16* WoS  = smem + 21504;        // [64][72] bytes [43008,52224) -- disjoint

    // ---- prologue: stage Wo^T (region untouched by main loop) ----
    // WoS[c][kk] = Wo[h*64+kk][c], coalesced f32 row reads
    for (int i = tid; i < 4096; i += 512) {
        const int kk = i >> 6, c = i & 63;
        WoS[c * 72 + kk] = __float2bfloat16(Wo[(size_t)(h * 64 + kk) * 64 + c]);
    }

    bf16x8 qf0[2], qf1[2];
#pragma unroll
    for (int rs = 0; rs < 2; rs++) {
        const int qrow = qt * 128 + rs * 64 + w4 * 16 + t16;
        qf0[rs] = *(const bf16x8*)(Qp + (size_t)qrow * 64 + 0  + quad * 8);
        qf1[rs] = *(const bf16x8*)(Qp + (size_t)qrow * 64 + 32 + quad * 8);
    }

    // constant all-ones B fragment for the l row-sum MFMA
    bf16x8 vones;
#pragma unroll
    for (int j = 0; j < 8; j++) vones[j] = (__bf16)1.0f;

    f32x4 Of[2][4];
    f32x4 Lf[2];
#pragma unroll
    for (int rs = 0; rs < 2; rs++) {
#pragma unroll
        for (int nt = 0; nt < 4; nt++) Of[rs][nt] = (f32x4){0.f, 0.f, 0.f, 0.f};
        Lf[rs] = (f32x4){0.f, 0.f, 0.f, 0.f};
    }

    // ---- register-prefetch staging: each thread owns 4 fixed 16B chunks ----
    const int r8s = tid >> 3;            // 0..63
    const int c8s = (tid & 7) << 3;      // 0..56
    bf16x8 pre[4];
#define LOAD_TILES(kt_)                                                          \
    do {                                                                         \
        pre[0] = *(const bf16x8*)&Kp [(size_t)((kt_) * 64 + r8s) * 64 + c8s];    \
        pre[1] = *(const bf16x8*)&Vtp[(size_t)r8s * SEQ + (kt_) * 64 + c8s];     \
        pre[2] = *(const bf16x8*)&Kp [(size_t)(512 + (kt_) * 64 + r8s) * 64 + c8s]; \
        pre[3] = *(const bf16x8*)&Vtp[(size_t)r8s * SEQ + 512 + (kt_) * 64 + c8s];  \
    } while (0)

    LOAD_TILES(0);

    for (int kt = 0; kt < 8; kt++) {
        *(bf16x8*)&KsB [       r8s * 72 + c8s] = pre[0];
        *(bf16x8*)&VtsB[       r8s * 72 + c8s] = pre[1];
        *(bf16x8*)&KsB [4608 + r8s * 72 + c8s] = pre[2];
        *(bf16x8*)&VtsB[4608 + r8s * 72 + c8s] = pre[3];
        __syncthreads();

        if (kt < 7) LOAD_TILES(kt + 1);   // latency hidden behind compute below

        const bf16* Ksw  = KsB  + kh * 4608;
        const bf16* Vtsw = VtsB + kh * 4608;

        // ---- Phase A: S^T = K Q^T (swapped), K frags read ONCE, both row-sets
        // Sf[rs][nt] lane layout: col=q=t16, row=kv=nt*16+quad*4+rr
        f32x4 Sf[2][4];
        __builtin_amdgcn_s_setprio(1);
#pragma unroll
        for (int nt = 0; nt < 4; nt++) {
            const bf16x8 kf0 = *(const bf16x8*)&Ksw[(nt * 16 + t16) * 72 + 0  + quad * 8];
            const bf16x8 kf1 = *(const bf16x8*)&Ksw[(nt * 16 + t16) * 72 + 32 + quad * 8];
#pragma unroll
            for (int rs = 0; rs < 2; rs++) {
                Sf[rs][nt] = (f32x4){0.f, 0.f, 0.f, 0.f};
                Sf[rs][nt] = __builtin_amdgcn_mfma_f32_16x16x32_bf16(kf0, qf0[rs], Sf[rs][nt], 0, 0, 0);
                Sf[rs][nt] = __builtin_amdgcn_mfma_f32_16x16x32_bf16(kf1, qf1[rs], Sf[rs][nt], 0, 0, 0);
            }
        }
        __builtin_amdgcn_s_setprio(0);

        // ---- Phase B: p = exp2(S), packed IN-REGISTER into sigma-ordered
        // A-frags: slot (quad,j) <-> kv = (j>=4)*16 + quad*4 + (j&3) (+32 hi).
        bf16x8 pfl[2], pfh[2];
#pragma unroll
        for (int rs = 0; rs < 2; rs++) {
            bf16 tl[8], th[8];
#pragma unroll
            for (int nt = 0; nt < 4; nt++)
#pragma unroll
                for (int rr = 0; rr < 4; rr++) {
                    const float p = __builtin_amdgcn_exp2f(Sf[rs][nt][rr]);
                    if (nt < 2) tl[nt * 4 + rr]       = __float2bfloat16(p);
                    else        th[(nt - 2) * 4 + rr] = __float2bfloat16(p);
                }
            pfl[rs] = *(bf16x8*)tl;
            pfh[rs] = *(bf16x8*)th;
        }

        // ---- Phase C: O += P V (+ l via ones MFMA); V read sigma-ordered ----
        __builtin_amdgcn_s_setprio(1);
#pragma unroll
        for (int nt = 0; nt < 4; nt++) {
            const int vrow = (nt * 16 + t16) * 72;
            bf16 vl[8], vh[8];
            *(bf16x4*)&vl[0] = *(const bf16x4*)&Vtsw[vrow + 0  + quad * 4];
            *(bf16x4*)&vl[4] = *(const bf16x4*)&Vtsw[vrow + 16 + quad * 4];
            *(bf16x4*)&vh[0] = *(const bf16x4*)&Vtsw[vrow + 32 + quad * 4];
            *(bf16x4*)&vh[4] = *(const bf16x4*)&Vtsw[vrow + 48 + quad * 4];
            const bf16x8 vf0 = *(const bf16x8*)vl;
            const bf16x8 vf1 = *(const bf16x8*)vh;
#pragma unroll
            for (int rs = 0; rs < 2; rs++) {
                Of[rs][nt] = __builtin_amdgcn_mfma_f32_16x16x32_bf16(pfl[rs], vf0, Of[rs][nt], 0, 0, 0);
                Of[rs][nt] = __builtin_amdgcn_mfma_f32_16x16x32_bf16(pfh[rs], vf1, Of[rs][nt], 0, 0, 0);
            }
        }
#pragma unroll
        for (int rs = 0; rs < 2; rs++) {
            Lf[rs] = __builtin_amdgcn_mfma_f32_16x16x32_bf16(pfl[rs], vones, Lf[rs], 0, 0, 0);
            Lf[rs] = __builtin_amdgcn_mfma_f32_16x16x32_bf16(pfh[rs], vones, Lf[rs], 0, 0, 0);
        }
        __builtin_amdgcn_s_setprio(0);
        __syncthreads();
    }
#undef LOAD_TILES

    // ---- epilogue: every wave owns group (w4, rs=kh) ----
    // kh-uniform register copies (no runtime-indexed ext-vector arrays):
    f32x4 Oown[4], Osend[4], Lown, Lsend;
    if (kh == 0) {
#pragma unroll
        for (int nt = 0; nt < 4; nt++) { Oown[nt] = Of[0][nt]; Osend[nt] = Of[1][nt]; }
        Lown = Lf[0]; Lsend = Lf[1];
    } else {
#pragma unroll
        for (int nt = 0; nt < 4; nt++) { Oown[nt] = Of[1][nt]; Osend[nt] = Of[0][nt]; }
        Lown = Lf[1]; Lsend = Lf[0];
    }

    // Overlay map (bytes from smem base, all 16B-aligned):
    //   Xch f32 [8 g][64 lane][17]      : [0, 34816)
    //   Lch f32x4 [8 g][64 lane]        : [34816, 43008)
    //   WoS bf16 [64][72]               : [43008, 52224)  (staged in prologue)
    //   Pe  bf16 [8 wave][16*72]        : [0, 18432)  -- after 2nd barrier
    float* Xch = (float*)smem;
    float* Lch = (float*)((char*)smem + 34816);
    bf16*  Pe  = smem;                  // overlays dead Xch

    {
        const int gwr = w4 * 2 + (1 - kh);   // group this wave SENDS
#pragma unroll
        for (int nt = 0; nt < 4; nt++)
#pragma unroll
            for (int rr = 0; rr < 4; rr++)
                Xch[(gwr * 64 + lane) * 17 + nt * 4 + rr] = Osend[nt][rr];
        *(f32x4*)&Lch[(gwr * 64 + lane) * 4] = Lsend;
    }
    __syncthreads();

    {
        const int grd = w4 * 2 + kh;         // group this wave OWNS
#pragma unroll
        for (int nt = 0; nt < 4; nt++)
#pragma unroll
            for (int rr = 0; rr < 4; rr++)
                Oown[nt][rr] += Xch[(grd * 64 + lane) * 17 + nt * 4 + rr];
        Lown += *(const f32x4*)&Lch[(grd * 64 + lane) * 4];
    }
    __syncthreads();   // Xch/Lch fully consumed -> Pe overlay safe

    {
        // normalize: Lown[rr] is the denom for Of row quad*4+rr (same keying)
        float inv_l[4];
#pragma unroll
        for (int rr = 0; rr < 4; rr++) inv_l[rr] = 1.0f / Lown[rr];

        bf16* Pew = Pe + wave * 1152;
#pragma unroll
        for (int nt = 0; nt < 4; nt++)
#pragma unroll
            for (int rr = 0; rr < 4; rr++)
                Pew[(quad * 4 + rr) * 72 + nt * 16 + t16] =
                    __float2bfloat16(Oown[nt][rr] * inv_l[rr]);

        const bf16x8 pf0 = *(const bf16x8*)&Pew[t16 * 72 + 0  + quad * 8];
        const bf16x8 pf1 = *(const bf16x8*)&Pew[t16 * 72 + 32 + quad * 8];

        f32x4 R[4];
#pragma unroll
        for (int nt = 0; nt < 4; nt++) {
            R[nt] = (f32x4){0.f, 0.f, 0.f, 0.f};
            const bf16x8 wf0 = *(const bf16x8*)&WoS[(nt * 16 + t16) * 72 + 0  + quad * 8];
            const bf16x8 wf1 = *(const bf16x8*)&WoS[(nt * 16 + t16) * 72 + 32 + quad * 8];
            R[nt] = __builtin_amdgcn_mfma_f32_16x16x32_bf16(pf0, wf0, R[nt], 0, 0, 0);
            R[nt] = __builtin_amdgcn_mfma_f32_16x16x32_bf16(pf1, wf1, R[nt], 0, 0, 0);
        }

        const int srow_base = qt * 128 + kh * 64 + w4 * 16 + quad * 4;
#pragma unroll
        for (int rr = 0; rr < 4; rr++) {
            const size_t base = ((size_t)b * SEQ + srow_base + rr) * 64;
#pragma unroll
            for (int nt = 0; nt < 4; nt++)
                atomicAdd(&out[base + nt * 16 + t16], R[nt][rr]);
        }
    }
}

// ---------------------------------------------------------------------------
extern "C" void kernel_launch(void* const* d_in, const int* in_sizes, int n_in,
                              void* d_out, int out_size, void* d_ws, size_t ws_size,
                              hipStream_t stream)
{
    const float* query = (const float*)d_in[0];
    const float* key_  = (const float*)d_in[1];
    const float* value = (const float*)d_in[2];
    const float* Wq    = (const float*)d_in[3];
    const float* bq    = (const float*)d_in[4];
    const float* Wk    = (const float*)d_in[5];
    const float* bk    = (const float*)d_in[6];
    const float* Wv    = (const float*)d_in[7];
    const float* bv    = (const float*)d_in[8];
    const float* Wo    = (const float*)d_in[9];
    const float* bo    = (const float*)d_in[10];
    // d_in[11..15] dead (softmax shift-invariance)

    float* out = (float*)d_out;
    char* ws   = (char*)d_ws;
    bf16* Qh = (bf16*)(ws + (size_t) 0 * 1024 * 1024);   // [B,H,S,64]  8 MB
    bf16* Kh = (bf16*)(ws + (size_t) 8 * 1024 * 1024);   //             8 MB
    bf16* Vt = (bf16*)(ws + (size_t)16 * 1024 * 1024);   // [B,H,64,S]  8 MB

    qkv_mfma_kernel<<<dim3(64, 8, 3), 256, 0, stream>>>(
        query, key_, value, Wq, Wk, Wv, bq, bk, bv, bo, out, Qh, Kh, Vt);
    flash_attn_kernel<<<dim3(64, 8), 512, 0, stream>>>(Qh, Kh, Vt, Wo, out);
}